// Round 1
// baseline (526.585 us; speedup 1.0000x reference)
//
#include <hip/hip_runtime.h>
#include <stdint.h>

#define DEV __device__ __forceinline__

typedef __attribute__((ext_vector_type(8))) short short8;
typedef __attribute__((ext_vector_type(8))) unsigned short ushort8;
typedef __attribute__((ext_vector_type(4))) float f32x4;
typedef __attribute__((ext_vector_type(4))) float floatx4;
typedef __attribute__((ext_vector_type(2))) unsigned int uint2v;

DEV unsigned short f2bf(float f) {
  union { float f; uint32_t u; } v; v.f = f;
  uint32_t u = v.u;
  u += 0x7FFFu + ((u >> 16) & 1);  // RNE
  return (unsigned short)(u >> 16);
}
DEV float bf2f(unsigned short s) {
  union { uint32_t u; float f; } v; v.u = ((uint32_t)s) << 16;
  return v.f;
}

DEV void async_ld16(void* lds, const void* g) {
  __builtin_amdgcn_global_load_lds(
      (const __attribute__((address_space(1))) unsigned int*)g,
      (__attribute__((address_space(3))) unsigned int*)lds, 16, 0, 0);
}

// ---------------- cast fp32 -> bf16 (vectorized) ----------------
__global__ __launch_bounds__(256) void cast_bf16_kernel(
    const float* __restrict__ in, unsigned short* __restrict__ out, int n) {
  int i = (blockIdx.x * 256 + threadIdx.x) * 4;
  if (i >= n) return;
  f32x4 v = *(const f32x4*)(in + i);
  union { unsigned short u[4]; uint2v v2; } o;
#pragma unroll
  for (int j = 0; j < 4; ++j) o.u[j] = f2bf(v[j]);
  *(uint2v*)(out + i) = o.v2;
}

// ------------- transpose + cast: in fp32 [R][C] -> out bf16 [C][R] -------------
__global__ __launch_bounds__(256) void transpose_cast_kernel(
    const float* __restrict__ in, unsigned short* __restrict__ out, int R, int C) {
  __shared__ float tile[32][33];
  const int c0 = blockIdx.x * 32, r0 = blockIdx.y * 32;
  const int tx = threadIdx.x & 31, ty = threadIdx.x >> 5;  // 32 x 8
#pragma unroll
  for (int i = 0; i < 32; i += 8)
    tile[ty + i][tx] = in[(size_t)(r0 + ty + i) * C + c0 + tx];
  __syncthreads();
#pragma unroll
  for (int i = 0; i < 32; i += 8)
    out[(size_t)(c0 + ty + i) * R + r0 + tx] = f2bf(tile[tx][ty + i]);
}

// ---------------- bf16 GEMM: C[M][N] = A[M][K] * Bt[N][K]^T ----------------
// 128x128 tile, BK=32, 4 waves (2x2), each wave 64x64 = 4x4 x mfma 16x16x32.
template <int OUT_BF16>
__global__ __launch_bounds__(256) void gemm_bt(
    const unsigned short* __restrict__ A, const unsigned short* __restrict__ Bt,
    void* __restrict__ Cout, int M, int Nn, int K) {
  __shared__ unsigned short As[128 * 32];
  __shared__ unsigned short Bs[128 * 32];
  const int t = threadIdx.x;
  const int lane = t & 63, w = t >> 6;
  const int wr = (w >> 1) * 64, wc = (w & 1) * 64;
  const int brow = blockIdx.y * 128, bcol = blockIdx.x * 128;
  const int l15 = lane & 15, lk = lane >> 4;

  f32x4 acc[4][4] = {};

  const size_t arow = (size_t)(brow + (t >> 2)) * K + (t & 3) * 8;
  const size_t brw  = (size_t)(bcol + (t >> 2)) * K + (t & 3) * 8;

  for (int kt = 0; kt < K; kt += 32) {
    async_ld16(&As[t * 8],        A + arow + kt);
    async_ld16(&As[t * 8 + 2048], A + arow + (size_t)64 * K + kt);
    async_ld16(&Bs[t * 8],        Bt + brw + kt);
    async_ld16(&Bs[t * 8 + 2048], Bt + brw + (size_t)64 * K + kt);
    asm volatile("s_waitcnt vmcnt(0)" ::: "memory");
    __syncthreads();
    short8 af[4], bfr[4];
#pragma unroll
    for (int m = 0; m < 4; ++m)
      af[m] = *(const short8*)&As[(wr + m * 16 + l15) * 32 + lk * 8];
#pragma unroll
    for (int n = 0; n < 4; ++n)
      bfr[n] = *(const short8*)&Bs[(wc + n * 16 + l15) * 32 + lk * 8];
#pragma unroll
    for (int m = 0; m < 4; ++m)
#pragma unroll
      for (int n = 0; n < 4; ++n)
        acc[m][n] = __builtin_amdgcn_mfma_f32_16x16x32_bf16(af[m], bfr[n], acc[m][n], 0, 0, 0);
    __syncthreads();
  }
#pragma unroll
  for (int m = 0; m < 4; ++m)
#pragma unroll
    for (int n = 0; n < 4; ++n)
#pragma unroll
      for (int j = 0; j < 4; ++j) {
        const int row = brow + wr + m * 16 + lk * 4 + j;  // D: row=(lane>>4)*4+reg
        const int col = bcol + wc + n * 16 + l15;         //    col=lane&15
        if (OUT_BF16)
          ((unsigned short*)Cout)[(size_t)row * Nn + col] = f2bf(acc[m][n][j]);
        else
          ((float*)Cout)[(size_t)row * Nn + col] = acc[m][n][j];
      }
}

// ------------- RoPE + pack: Y bf16 [B*N][6144] -> Qb,Kb [B,H,N,128], Vt [B,H,128,N] -------------
__global__ __launch_bounds__(256) void rope_pack(
    const unsigned short* __restrict__ Y, const int* __restrict__ pos,
    unsigned short* __restrict__ Qb, unsigned short* __restrict__ Kb,
    unsigned short* __restrict__ Vt, int N) {
  __shared__ unsigned short vt[128 * 32];
  const int bh = blockIdx.x, b = bh >> 4, h = bh & 15;
  const int n0 = blockIdx.y * 32;
  const int t = threadIdx.x;
  const int tok = t >> 3, dp0 = (t & 7) * 8;  // 8 threads/token, 8 d-pairs each
  const int n = n0 + tok;
  const float p = (float)pos[b * N + n];
  const size_t yb = (size_t)(b * N + n) * 6144 + h * 128;

  ushort8 qlo = *(const ushort8*)&Y[yb + dp0];
  ushort8 qhi = *(const ushort8*)&Y[yb + dp0 + 64];
  ushort8 klo = *(const ushort8*)&Y[yb + 2048 + dp0];
  ushort8 khi = *(const ushort8*)&Y[yb + 2048 + dp0 + 64];
  ushort8 vlo = *(const ushort8*)&Y[yb + 4096 + dp0];
  ushort8 vhi = *(const ushort8*)&Y[yb + 4096 + dp0 + 64];

  ushort8 oql, oqh, okl, okh;
#pragma unroll
  for (int i = 0; i < 8; ++i) {
    const float d = (float)(dp0 + i);
    // inv_freq = 10000^(-d/64) = 2^(-d*log2(10000)/64)
    const float ang = p * exp2f(d * -0.2076205059304601f);
    const float s = sinf(ang), c = cosf(ang);
    const float ql = bf2f(qlo[i]), qh = bf2f(qhi[i]);
    const float kl = bf2f(klo[i]), kh = bf2f(khi[i]);
    oql[i] = f2bf(ql * c - qh * s);
    oqh[i] = f2bf(qh * c + ql * s);
    okl[i] = f2bf(kl * c - kh * s);
    okh[i] = f2bf(kh * c + kl * s);
    vt[(dp0 + i) * 32 + tok] = vlo[i];
    vt[(dp0 + 64 + i) * 32 + tok] = vhi[i];
  }
  const size_t qb = ((size_t)bh * N + n) * 128;
  *(ushort8*)&Qb[qb + dp0] = oql;
  *(ushort8*)&Qb[qb + dp0 + 64] = oqh;
  *(ushort8*)&Kb[qb + dp0] = okl;
  *(ushort8*)&Kb[qb + dp0 + 64] = okh;
  __syncthreads();
  const int d = t >> 1, half = t & 1;
  const size_t vdst = (size_t)bh * 128 * N + (size_t)d * N + n0 + half * 16;
  *(ushort8*)&Vt[vdst]     = *(const ushort8*)&vt[d * 32 + half * 16];
  *(ushort8*)&Vt[vdst + 8] = *(const ushort8*)&vt[d * 32 + half * 16 + 8];
}

// ------------- causal flash attention, bf16 MFMA -------------
// block = 4 waves; each wave owns 16 q rows, iterates kv tiles of 32.
// S^T = mfma(K, Q): D[kv][q] with q = lane&15 -> per-q stats reduce via shfl_xor 16/32.
__global__ __launch_bounds__(256) void flash_attn(
    const unsigned short* __restrict__ Qb, const unsigned short* __restrict__ Kb,
    const unsigned short* __restrict__ Vt, unsigned short* __restrict__ Ao, int N) {
  __shared__ unsigned short plds[4 * 512];  // per-wave 16x32 bf16 P bounce
  const int t = threadIdx.x, lane = t & 63, w = t >> 6;
  const int bh = blockIdx.x, b = bh >> 4, h = bh & 15;
  const int q0 = blockIdx.y * 64 + w * 16;
  const int l15 = lane & 15, lk = lane >> 4;
  const size_t base = (size_t)bh * N * 128;
  const size_t vbase = (size_t)bh * 128 * N;
  unsigned short* pl = &plds[w * 512];

  short8 qf[4];
#pragma unroll
  for (int kk = 0; kk < 4; ++kk)
    qf[kk] = *(const short8*)&Qb[base + (size_t)(q0 + l15) * 128 + kk * 32 + lk * 8];

  f32x4 acc[8] = {};
  float m_run = -__builtin_inff(), l_run = 0.f;
  const float scale = 0.08838834764831845f;  // 128^-0.5

  for (int kv0 = 0; kv0 < q0 + 16; kv0 += 32) {
    f32x4 st[2] = {};
#pragma unroll
    for (int h2 = 0; h2 < 2; ++h2) {
#pragma unroll
      for (int kk = 0; kk < 4; ++kk) {
        short8 kf = *(const short8*)&Kb[base + (size_t)(kv0 + h2 * 16 + l15) * 128 + kk * 32 + lk * 8];
        st[h2] = __builtin_amdgcn_mfma_f32_16x16x32_bf16(kf, qf[kk], st[h2], 0, 0, 0);
      }
    }
    const int qg = q0 + l15;
    float sv[8];
    float mt = -__builtin_inff();
#pragma unroll
    for (int h2 = 0; h2 < 2; ++h2)
#pragma unroll
      for (int j = 0; j < 4; ++j) {
        const int kvg = kv0 + h2 * 16 + lk * 4 + j;  // D row = kv
        float s = st[h2][j] * scale;
        s = (kvg > qg) ? -__builtin_inff() : s;
        sv[h2 * 4 + j] = s;
        mt = fmaxf(mt, s);
      }
    mt = fmaxf(mt, __shfl_xor(mt, 16));
    mt = fmaxf(mt, __shfl_xor(mt, 32));
    const float m_new = fmaxf(m_run, mt);
    const float alpha = __expf(m_run - m_new);
    float lsum = 0.f;
    unsigned short pb[8];
#pragma unroll
    for (int i = 0; i < 8; ++i) {
      const float pv = __expf(sv[i] - m_new);
      lsum += pv;
      pb[i] = f2bf(pv);
    }
    lsum += __shfl_xor(lsum, 16);
    lsum += __shfl_xor(lsum, 32);
    l_run = l_run * alpha + lsum;
    m_run = m_new;

    float alD[4];
#pragma unroll
    for (int j = 0; j < 4; ++j) alD[j] = __shfl(alpha, lk * 4 + j);
#pragma unroll
    for (int dblk = 0; dblk < 8; ++dblk)
#pragma unroll
      for (int j = 0; j < 4; ++j) acc[dblk][j] *= alD[j];

    // bounce P^T (S^T layout) -> P[q][kv] in LDS, per-wave private region
#pragma unroll
    for (int h2 = 0; h2 < 2; ++h2) {
      union { unsigned short u[4]; uint2v v; } pk;
#pragma unroll
      for (int j = 0; j < 4; ++j) pk.u[j] = pb[h2 * 4 + j];
      *(uint2v*)&pl[l15 * 32 + h2 * 16 + lk * 4] = pk.v;
    }
    asm volatile("s_waitcnt lgkmcnt(0)" ::: "memory");
    const short8 pa = *(const short8*)&pl[l15 * 32 + lk * 8];

#pragma unroll
    for (int dblk = 0; dblk < 8; ++dblk) {
      short8 vf = *(const short8*)&Vt[vbase + (size_t)(dblk * 16 + l15) * N + kv0 + lk * 8];
      acc[dblk] = __builtin_amdgcn_mfma_f32_16x16x32_bf16(pa, vf, acc[dblk], 0, 0, 0);
    }
  }

  const float inv = 1.0f / l_run;
  float invD[4];
#pragma unroll
  for (int j = 0; j < 4; ++j) invD[j] = __shfl(inv, lk * 4 + j);
#pragma unroll
  for (int dblk = 0; dblk < 8; ++dblk)
#pragma unroll
    for (int j = 0; j < 4; ++j) {
      const int row = b * N + q0 + lk * 4 + j;            // token
      const int col = h * 128 + dblk * 16 + l15;          // channel
      Ao[(size_t)row * 2048 + col] = f2bf(acc[dblk][j] * invD[j]);
    }
}

extern "C" void kernel_launch(void* const* d_in, const int* in_sizes, int n_in,
                              void* d_out, int out_size, void* d_ws, size_t ws_size,
                              hipStream_t stream) {
  const float* x      = (const float*)d_in[0];
  const int*   pos    = (const int*)d_in[1];
  const float* Wqkv   = (const float*)d_in[2];
  const float* Wproj  = (const float*)d_in[3];
  float* out = (float*)d_out;

  const int N = 2048, C = 2048;
  const int M = 2 * N;  // 4096 tokens

  char* ws = (char*)d_ws;
  unsigned short* Xb      = (unsigned short*)(ws + 0);            // 16 MiB, reused as Ao
  unsigned short* Wqkv_t  = (unsigned short*)(ws + 16777216);     // 24 MiB
  unsigned short* Wproj_t = (unsigned short*)(ws + 41943040);     // 8 MiB
  unsigned short* Y       = (unsigned short*)(ws + 50331648);     // 48 MiB (bf16 QKV)
  unsigned short* Qb      = (unsigned short*)(ws + 100663296);    // 16 MiB
  unsigned short* Kb      = (unsigned short*)(ws + 117440512);    // 16 MiB
  unsigned short* Vt      = (unsigned short*)(ws + 134217728);    // 16 MiB -> 144 MiB total
  unsigned short* Ao = Xb;

  // 1. casts
  cast_bf16_kernel<<<(M * C) / 1024, 256, 0, stream>>>(x, Xb, M * C);
  transpose_cast_kernel<<<dim3(3 * C / 32, C / 32), 256, 0, stream>>>(Wqkv, Wqkv_t, C, 3 * C);
  transpose_cast_kernel<<<dim3(C / 32, C / 32), 256, 0, stream>>>(Wproj, Wproj_t, C, C);
  // 2. QKV projection: Y[M][6144] bf16
  gemm_bt<1><<<dim3(3 * C / 128, M / 128), 256, 0, stream>>>(Xb, Wqkv_t, Y, M, 3 * C, C);
  // 3. RoPE + repack
  rope_pack<<<dim3(32, N / 32), 256, 0, stream>>>(Y, pos, Qb, Kb, Vt, N);
  // 4. causal attention -> Ao bf16 [M][C]
  flash_attn<<<dim3(32, N / 64), 256, 0, stream>>>(Qb, Kb, Vt, Ao, N);
  // 5. output projection -> fp32 d_out
  gemm_bt<0><<<dim3(C / 128, M / 128), 256, 0, stream>>>(Ao, Wproj_t, out, M, C, C);
}

// Round 2
// 483.102 us; speedup vs baseline: 1.0900x; 1.0900x over previous
//
#include <hip/hip_runtime.h>
#include <stdint.h>

#define DEV __device__ __forceinline__

typedef __attribute__((ext_vector_type(8))) short short8;
typedef __attribute__((ext_vector_type(8))) unsigned short ushort8;
typedef __attribute__((ext_vector_type(4))) float f32x4;
typedef __attribute__((ext_vector_type(2))) unsigned int uint2v;

DEV unsigned short f2bf(float f) {
  union { float f; uint32_t u; } v; v.f = f;
  uint32_t u = v.u;
  u += 0x7FFFu + ((u >> 16) & 1);  // RNE
  return (unsigned short)(u >> 16);
}
DEV float bf2f(unsigned short s) {
  union { uint32_t u; float f; } v; v.u = ((uint32_t)s) << 16;
  return v.f;
}

DEV void async_ld16(void* lds, const void* g) {
  __builtin_amdgcn_global_load_lds(
      (const __attribute__((address_space(1))) unsigned int*)g,
      (__attribute__((address_space(3))) unsigned int*)lds, 16, 0, 0);
}

// ---------------- cast fp32 -> bf16 (vectorized) ----------------
__global__ __launch_bounds__(256) void cast_bf16_kernel(
    const float* __restrict__ in, unsigned short* __restrict__ out, int n) {
  int i = (blockIdx.x * 256 + threadIdx.x) * 4;
  if (i >= n) return;
  f32x4 v = *(const f32x4*)(in + i);
  union { unsigned short u[4]; uint2v v2; } o;
#pragma unroll
  for (int j = 0; j < 4; ++j) o.u[j] = f2bf(v[j]);
  *(uint2v*)(out + i) = o.v2;
}

// ------------- transpose + cast: in fp32 [R][C] -> out bf16 [C][R] -------------
__global__ __launch_bounds__(256) void transpose_cast_kernel(
    const float* __restrict__ in, unsigned short* __restrict__ out, int R, int C) {
  __shared__ float tile[32][33];
  const int c0 = blockIdx.x * 32, r0 = blockIdx.y * 32;
  const int tx = threadIdx.x & 31, ty = threadIdx.x >> 5;  // 32 x 8
#pragma unroll
  for (int i = 0; i < 32; i += 8)
    tile[ty + i][tx] = in[(size_t)(r0 + ty + i) * C + c0 + tx];
  __syncthreads();
#pragma unroll
  for (int i = 0; i < 32; i += 8)
    out[(size_t)(c0 + ty + i) * R + r0 + tx] = f2bf(tile[tx][ty + i]);
}

// ---------------- bf16 GEMM: C[M][N] = A[M][K] * Bt[N][K]^T ----------------
// 128x128 tile, BK=32, 4 waves (2x2), each wave 64x64 = 4x4 x mfma 16x16x32.
template <int OUT_BF16>
__global__ __launch_bounds__(256) void gemm_bt(
    const unsigned short* __restrict__ A, const unsigned short* __restrict__ Bt,
    void* __restrict__ Cout, int M, int Nn, int K) {
  __shared__ unsigned short As[128 * 32];
  __shared__ unsigned short Bs[128 * 32];
  const int t = threadIdx.x;
  const int lane = t & 63, w = t >> 6;
  const int wr = (w >> 1) * 64, wc = (w & 1) * 64;
  const int brow = blockIdx.y * 128, bcol = blockIdx.x * 128;
  const int l15 = lane & 15, lk = lane >> 4;

  f32x4 acc[4][4] = {};

  const size_t arow = (size_t)(brow + (t >> 2)) * K + (t & 3) * 8;
  const size_t brw  = (size_t)(bcol + (t >> 2)) * K + (t & 3) * 8;

  for (int kt = 0; kt < K; kt += 32) {
    async_ld16(&As[t * 8],        A + arow + kt);
    async_ld16(&As[t * 8 + 2048], A + arow + (size_t)64 * K + kt);
    async_ld16(&Bs[t * 8],        Bt + brw + kt);
    async_ld16(&Bs[t * 8 + 2048], Bt + brw + (size_t)64 * K + kt);
    asm volatile("s_waitcnt vmcnt(0)" ::: "memory");
    __syncthreads();
    short8 af[4], bfr[4];
#pragma unroll
    for (int m = 0; m < 4; ++m)
      af[m] = *(const short8*)&As[(wr + m * 16 + l15) * 32 + lk * 8];
#pragma unroll
    for (int n = 0; n < 4; ++n)
      bfr[n] = *(const short8*)&Bs[(wc + n * 16 + l15) * 32 + lk * 8];
#pragma unroll
    for (int m = 0; m < 4; ++m)
#pragma unroll
      for (int n = 0; n < 4; ++n)
        acc[m][n] = __builtin_amdgcn_mfma_f32_16x16x32_bf16(af[m], bfr[n], acc[m][n], 0, 0, 0);
    __syncthreads();
  }
#pragma unroll
  for (int m = 0; m < 4; ++m)
#pragma unroll
    for (int n = 0; n < 4; ++n)
#pragma unroll
      for (int j = 0; j < 4; ++j) {
        const int row = brow + wr + m * 16 + lk * 4 + j;  // D: row=(lane>>4)*4+reg
        const int col = bcol + wc + n * 16 + l15;         //    col=lane&15
        if (OUT_BF16)
          ((unsigned short*)Cout)[(size_t)row * Nn + col] = f2bf(acc[m][n][j]);
        else
          ((float*)Cout)[(size_t)row * Nn + col] = acc[m][n][j];
      }
}

// ------------- RoPE + pack: Y bf16 [B*N][6144] -> Qb,Kb [B,H,N,128], Vt [B,H,128,N] -------------
__global__ __launch_bounds__(256) void rope_pack(
    const unsigned short* __restrict__ Y, const int* __restrict__ pos,
    unsigned short* __restrict__ Qb, unsigned short* __restrict__ Kb,
    unsigned short* __restrict__ Vt, int N) {
  __shared__ unsigned short vt[128 * 32];
  const int bh = blockIdx.x, b = bh >> 4, h = bh & 15;
  const int n0 = blockIdx.y * 32;
  const int t = threadIdx.x;
  const int tok = t >> 3, dp0 = (t & 7) * 8;  // 8 threads/token, 8 d-pairs each
  const int n = n0 + tok;
  const float p = (float)pos[b * N + n];
  const size_t yb = (size_t)(b * N + n) * 6144 + h * 128;

  ushort8 qlo = *(const ushort8*)&Y[yb + dp0];
  ushort8 qhi = *(const ushort8*)&Y[yb + dp0 + 64];
  ushort8 klo = *(const ushort8*)&Y[yb + 2048 + dp0];
  ushort8 khi = *(const ushort8*)&Y[yb + 2048 + dp0 + 64];
  ushort8 vlo = *(const ushort8*)&Y[yb + 4096 + dp0];
  ushort8 vhi = *(const ushort8*)&Y[yb + 4096 + dp0 + 64];

  ushort8 oql, oqh, okl, okh;
#pragma unroll
  for (int i = 0; i < 8; ++i) {
    const float d = (float)(dp0 + i);
    const float ang = p * exp2f(d * -0.2076205059304601f);
    const float s = sinf(ang), c = cosf(ang);
    const float ql = bf2f(qlo[i]), qh = bf2f(qhi[i]);
    const float kl = bf2f(klo[i]), kh = bf2f(khi[i]);
    oql[i] = f2bf(ql * c - qh * s);
    oqh[i] = f2bf(qh * c + ql * s);
    okl[i] = f2bf(kl * c - kh * s);
    okh[i] = f2bf(kh * c + kl * s);
    vt[(dp0 + i) * 32 + tok] = vlo[i];
    vt[(dp0 + 64 + i) * 32 + tok] = vhi[i];
  }
  const size_t qb = ((size_t)bh * N + n) * 128;
  *(ushort8*)&Qb[qb + dp0] = oql;
  *(ushort8*)&Qb[qb + dp0 + 64] = oqh;
  *(ushort8*)&Kb[qb + dp0] = okl;
  *(ushort8*)&Kb[qb + dp0 + 64] = okh;
  __syncthreads();
  const int d = t >> 1, half = t & 1;
  const size_t vdst = (size_t)bh * 128 * N + (size_t)d * N + n0 + half * 16;
  *(ushort8*)&Vt[vdst]     = *(const ushort8*)&vt[d * 32 + half * 16];
  *(ushort8*)&Vt[vdst + 8] = *(const ushort8*)&vt[d * 32 + half * 16 + 8];
}

// ------------- causal flash attention, bf16 MFMA, K register ping-pong -------------
// block = 4 waves; each wave owns 16 q rows, iterates kv tiles of 32.
// S^T = mfma(K, Q): D[kv][q] with q = lane&15 -> per-q stats reduce via shfl_xor 16/32.
// K fragments for tile t+1 are prefetched (register double-buffer) while tile t computes;
// V fragments for tile t are issued before QK^T so softmax hides their latency.
__global__ __launch_bounds__(256) void flash_attn(
    const unsigned short* __restrict__ Qb, const unsigned short* __restrict__ Kb,
    const unsigned short* __restrict__ Vt, unsigned short* __restrict__ Ao, int N) {
  __shared__ unsigned short plds[4 * 512];  // per-wave 16x32 bf16 P bounce
  const int t = threadIdx.x, lane = t & 63, w = t >> 6;
  const int bh = blockIdx.x, b = bh >> 4, h = bh & 15;
  const int by = gridDim.y - 1 - blockIdx.y;  // heavy q-tiles dispatch first
  const int q0 = by * 64 + w * 16;
  const int l15 = lane & 15, lk = lane >> 4;
  const size_t base = (size_t)bh * N * 128;
  const size_t vbase = (size_t)bh * 128 * N;
  unsigned short* pl = &plds[w * 512];

  short8 qf[4];
#pragma unroll
  for (int kk = 0; kk < 4; ++kk)
    qf[kk] = *(const short8*)&Qb[base + (size_t)(q0 + l15) * 128 + kk * 32 + lk * 8];

  f32x4 acc[8] = {};
  float m_run = -__builtin_inff(), l_run = 0.f;
  const float scale = 0.08838834764831845f;  // 128^-0.5
  const int qg = q0 + l15;

  auto loadK = [&](short8(&kb)[8], int tile) {
#pragma unroll
    for (int h2 = 0; h2 < 2; ++h2)
#pragma unroll
      for (int kk = 0; kk < 4; ++kk)
        kb[h2 * 4 + kk] = *(const short8*)&Kb[base + (size_t)(tile * 32 + h2 * 16 + l15) * 128 + kk * 32 + lk * 8];
  };

  auto computeTile = [&](short8(&kb)[8], int tile, short8(&kn)[8], int ntile) {
    const int kv0 = tile * 32;
    // issue V loads for THIS tile first (softmax hides their latency)
    short8 vf[8];
#pragma unroll
    for (int dblk = 0; dblk < 8; ++dblk)
      vf[dblk] = *(const short8*)&Vt[vbase + (size_t)(dblk * 16 + l15) * N + kv0 + lk * 8];
    // prefetch next K tile (consumed next iteration)
    loadK(kn, ntile);

    f32x4 st[2] = {};
    __builtin_amdgcn_s_setprio(1);
#pragma unroll
    for (int h2 = 0; h2 < 2; ++h2)
#pragma unroll
      for (int kk = 0; kk < 4; ++kk)
        st[h2] = __builtin_amdgcn_mfma_f32_16x16x32_bf16(kb[h2 * 4 + kk], qf[kk], st[h2], 0, 0, 0);
    __builtin_amdgcn_s_setprio(0);

    float sv[8];
    float mt = -__builtin_inff();
#pragma unroll
    for (int h2 = 0; h2 < 2; ++h2)
#pragma unroll
      for (int j = 0; j < 4; ++j) {
        const int kvg = kv0 + h2 * 16 + lk * 4 + j;  // D row = kv
        float s = st[h2][j] * scale;
        s = (kvg > qg) ? -__builtin_inff() : s;
        sv[h2 * 4 + j] = s;
        mt = fmaxf(mt, s);
      }
    mt = fmaxf(mt, __shfl_xor(mt, 16));
    mt = fmaxf(mt, __shfl_xor(mt, 32));
    const float m_new = fmaxf(m_run, mt);
    const float alpha = __expf(m_run - m_new);
    float lsum = 0.f;
    unsigned short pb[8];
#pragma unroll
    for (int i = 0; i < 8; ++i) {
      const float pv = __expf(sv[i] - m_new);
      lsum += pv;
      pb[i] = f2bf(pv);
    }
    lsum += __shfl_xor(lsum, 16);
    lsum += __shfl_xor(lsum, 32);
    l_run = l_run * alpha + lsum;
    m_run = m_new;

    float alD[4];
#pragma unroll
    for (int j = 0; j < 4; ++j) alD[j] = __shfl(alpha, lk * 4 + j);
#pragma unroll
    for (int dblk = 0; dblk < 8; ++dblk)
#pragma unroll
      for (int j = 0; j < 4; ++j) acc[dblk][j] *= alD[j];

    // bounce P^T (S^T layout) -> P[q][kv] in LDS, per-wave private region
#pragma unroll
    for (int h2 = 0; h2 < 2; ++h2) {
      union { unsigned short u[4]; uint2v v; } pk;
#pragma unroll
      for (int j = 0; j < 4; ++j) pk.u[j] = pb[h2 * 4 + j];
      *(uint2v*)&pl[l15 * 32 + h2 * 16 + lk * 4] = pk.v;
    }
    asm volatile("s_waitcnt lgkmcnt(0)" ::: "memory");
    const short8 pa = *(const short8*)&pl[l15 * 32 + lk * 8];

    __builtin_amdgcn_s_setprio(1);
#pragma unroll
    for (int dblk = 0; dblk < 8; ++dblk)
      acc[dblk] = __builtin_amdgcn_mfma_f32_16x16x32_bf16(pa, vf[dblk], acc[dblk], 0, 0, 0);
    __builtin_amdgcn_s_setprio(0);
  };

  const int T = q0 / 32 + 1;  // number of 32-wide kv tiles for this wave
  short8 kA[8], kB[8];
  loadK(kA, 0);
  int tt = 0;
  while (true) {
    {
      const int nt = (tt + 1 < T) ? tt + 1 : T - 1;
      computeTile(kA, tt, kB, nt);
    }
    if (++tt >= T) break;
    {
      const int nt = (tt + 1 < T) ? tt + 1 : T - 1;
      computeTile(kB, tt, kA, nt);
    }
    if (++tt >= T) break;
  }

  const float inv = 1.0f / l_run;
  float invD[4];
#pragma unroll
  for (int j = 0; j < 4; ++j) invD[j] = __shfl(inv, lk * 4 + j);
#pragma unroll
  for (int dblk = 0; dblk < 8; ++dblk)
#pragma unroll
    for (int j = 0; j < 4; ++j) {
      const int row = b * N + q0 + lk * 4 + j;            // token
      const int col = h * 128 + dblk * 16 + l15;          // channel
      Ao[(size_t)row * 2048 + col] = f2bf(acc[dblk][j] * invD[j]);
    }
}

extern "C" void kernel_launch(void* const* d_in, const int* in_sizes, int n_in,
                              void* d_out, int out_size, void* d_ws, size_t ws_size,
                              hipStream_t stream) {
  const float* x      = (const float*)d_in[0];
  const int*   pos    = (const int*)d_in[1];
  const float* Wqkv   = (const float*)d_in[2];
  const float* Wproj  = (const float*)d_in[3];
  float* out = (float*)d_out;

  const int N = 2048, C = 2048;
  const int M = 2 * N;  // 4096 tokens

  char* ws = (char*)d_ws;
  unsigned short* Xb      = (unsigned short*)(ws + 0);            // 16 MiB, reused as Ao
  unsigned short* Wqkv_t  = (unsigned short*)(ws + 16777216);     // 24 MiB
  unsigned short* Wproj_t = (unsigned short*)(ws + 41943040);     // 8 MiB
  unsigned short* Y       = (unsigned short*)(ws + 50331648);     // 48 MiB (bf16 QKV)
  unsigned short* Qb      = (unsigned short*)(ws + 100663296);    // 16 MiB
  unsigned short* Kb      = (unsigned short*)(ws + 117440512);    // 16 MiB
  unsigned short* Vt      = (unsigned short*)(ws + 134217728);    // 16 MiB -> 144 MiB total
  unsigned short* Ao = Xb;

  // 1. casts
  cast_bf16_kernel<<<(M * C) / 1024, 256, 0, stream>>>(x, Xb, M * C);
  transpose_cast_kernel<<<dim3(3 * C / 32, C / 32), 256, 0, stream>>>(Wqkv, Wqkv_t, C, 3 * C);
  transpose_cast_kernel<<<dim3(C / 32, C / 32), 256, 0, stream>>>(Wproj, Wproj_t, C, C);
  // 2. QKV projection: Y[M][6144] bf16
  gemm_bt<1><<<dim3(3 * C / 128, M / 128), 256, 0, stream>>>(Xb, Wqkv_t, Y, M, 3 * C, C);
  // 3. RoPE + repack
  rope_pack<<<dim3(32, N / 32), 256, 0, stream>>>(Y, pos, Qb, Kb, Vt, N);
  // 4. causal attention -> Ao bf16 [M][C]
  flash_attn<<<dim3(32, N / 64), 256, 0, stream>>>(Qb, Kb, Vt, Ao, N);
  // 5. output projection -> fp32 d_out
  gemm_bt<0><<<dim3(C / 128, M / 128), 256, 0, stream>>>(Ao, Wproj_t, out, M, C, C);
}